// Round 4
// baseline (744.537 us; speedup 1.0000x reference)
//
#include <hip/hip_runtime.h>
#include <stdint.h>
#include <stddef.h>

typedef __attribute__((ext_vector_type(8))) short bf16x8;
typedef __attribute__((ext_vector_type(4))) float f32x4;
typedef __attribute__((ext_vector_type(8))) unsigned short u16x8;
typedef __attribute__((ext_vector_type(4))) unsigned short u16x4;
typedef __attribute__((ext_vector_type(2))) unsigned short u16x2;

#define DEVINL __device__ __forceinline__

DEVINL unsigned short f2b(float x){
  union { float f; unsigned int u; } v; v.f = x;
  return (unsigned short)((v.u + 0x7FFFu + ((v.u >> 16) & 1u)) >> 16);
}
DEVINL float b2f(unsigned short h){
  union { float f; unsigned int u; } v; v.u = ((unsigned int)h) << 16;
  return v.f;
}

DEVINL void gl_lds16(void* g, void* lds){
  __builtin_amdgcn_global_load_lds(
      (__attribute__((address_space(1))) void*)g,
      (__attribute__((address_space(3))) void*)lds, 16, 0, 0);
}

// ---------------------------------------------------------------------------
// prep: transpose+cast weights to bf16 [n][k]; fold 1/16 into wq; fold BN.
// ---------------------------------------------------------------------------
__global__ __launch_bounds__(256) void prep_k(
    const float* __restrict__ m1w2, const float* __restrict__ m2w2,
    const float* __restrict__ wqp,  const float* __restrict__ wkp,
    const float* __restrict__ wvp,  const float* __restrict__ wop,
    const float* __restrict__ tdw,  const float* __restrict__ tdb,
    const float* __restrict__ bng,  const float* __restrict__ bnb,
    const float* __restrict__ bnm,  const float* __restrict__ bnv,
    unsigned short* __restrict__ wT, float* __restrict__ bns, float* __restrict__ bnt)
{
  int idx = blockIdx.x * 256 + threadIdx.x;
  if (idx < 786432){
    int mat = idx >> 17;
    int e   = idx & 131071;
    int i   = e >> 16;
    int eb  = e & 65535;
    int n = eb >> 8, kx = eb & 255;
    const float* src; float sc = 1.0f;
    if      (mat == 0) src = m1w2;
    else if (mat == 1) src = m2w2;
    else if (mat == 2){ src = wqp; sc = 0.0625f; }
    else if (mat == 3) src = wkp;
    else if (mat == 4) src = wvp;
    else               src = wop;
    wT[idx] = f2b(src[i*65536 + kx*256 + n] * sc);
  } else if (idx < 917504){
    int e = idx - 786432;
    int n = e >> 8, kx = e & 255;
    wT[786432 + e] = f2b(tdw[kx*512 + n]);
  } else if (idx < 918016){
    int c = idx - 917504;
    float s = bng[c] * rsqrtf(bnv[c] + 1e-5f);
    bns[c] = s;
    bnt[c] = (tdb[c] - bnm[c]) * s + bnb[c];
  }
}

// ---------------------------------------------------------------------------
// Generic GEMM (m97-style), used only for the final td+BN (N=512).
// ---------------------------------------------------------------------------
__global__ __launch_bounds__(256) void gemm_k(
    const unsigned short* __restrict__ A,
    const unsigned short* __restrict__ Wt,
    unsigned short* __restrict__ out,
    const float* __restrict__ bias,
    const unsigned short* __restrict__ addend,
    const float* __restrict__ bn_s,
    const float* __restrict__ bn_t,
    int ldc)
{
  __shared__ __attribute__((aligned(16))) unsigned short aT[512*8];
  __shared__ __attribute__((aligned(16))) unsigned short bT[512*8];
  __shared__ __attribute__((aligned(16))) unsigned short epi[128*140];

  const int tid  = threadIdx.x;
  const int lane = tid & 63;
  const int wave = tid >> 6;
  const int lrow = lane & 15, lq = lane >> 4;
  const int wr = wave >> 1, wc = wave & 1;
  const int m0 = blockIdx.x * 128;
  const int n0 = blockIdx.y * 128;

  f32x4 acc[4][4] = {};

  int aOff[4], bOff[4];
#pragma unroll
  for (int mt = 0; mt < 4; mt++){
    int row = wr*64 + mt*16 + lrow;
    aOff[mt] = row*64 + ((lq ^ ((row >> 1) & 3)) << 4);
  }
#pragma unroll
  for (int nt = 0; nt < 4; nt++){
    int row = wc*64 + nt*16 + lrow;
    bOff[nt] = row*64 + ((lq ^ ((row >> 1) & 3)) << 4);
  }

  const int s0 = tid, s1 = tid + 256;
  const int r0 = s0 >> 2, kc0 = (s0 & 3) ^ ((r0 >> 1) & 3);
  const int r1 = s1 >> 2, kc1 = (s1 & 3) ^ ((r1 >> 1) & 3);
  const unsigned short* Ab = A  + (size_t)m0 * 256;
  const unsigned short* Bb = Wt + (size_t)n0 * 256;
  char* aL = (char*)aT;
  char* bL = (char*)bT;
  const int wslot = wave * 64 * 16;

  for (int k0 = 0; k0 < 256; k0 += 32){
    __syncthreads();
    gl_lds16((void*)(Ab + r0*256 + k0 + kc0*8), aL + wslot);
    gl_lds16((void*)(Ab + r1*256 + k0 + kc1*8), aL + 4096 + wslot);
    gl_lds16((void*)(Bb + r0*256 + k0 + kc0*8), bL + wslot);
    gl_lds16((void*)(Bb + r1*256 + k0 + kc1*8), bL + 4096 + wslot);
    __syncthreads();
    bf16x8 af[4], bfr[4];
#pragma unroll
    for (int mt = 0; mt < 4; mt++) af[mt]  = *(const bf16x8*)(aL + aOff[mt]);
#pragma unroll
    for (int nt = 0; nt < 4; nt++) bfr[nt] = *(const bf16x8*)(bL + bOff[nt]);
#pragma unroll
    for (int mt = 0; mt < 4; mt++)
#pragma unroll
      for (int nt = 0; nt < 4; nt++)
        acc[mt][nt] = __builtin_amdgcn_mfma_f32_16x16x32_bf16(af[mt], bfr[nt], acc[mt][nt], 0, 0, 0);
  }

  __syncthreads();
#pragma unroll
  for (int mt = 0; mt < 4; mt++){
    int row = wr*64 + mt*16 + lq*4;
#pragma unroll
    for (int nt = 0; nt < 4; nt++){
      int col = wc*64 + nt*16 + lrow;
#pragma unroll
      for (int r = 0; r < 4; r++)
        epi[(row + r)*140 + col] = f2b(acc[mt][nt][r]);
    }
  }
  __syncthreads();

  const int erow = tid >> 1, h = tid & 1;
  const size_t gbase = (size_t)(m0 + erow) * (size_t)ldc + n0;
#pragma unroll
  for (int i = 0; i < 8; i++){
    int col = h*64 + i*8;
    u16x4 lo = *(const u16x4*)(&epi[erow*140 + col]);
    u16x4 hi = *(const u16x4*)(&epi[erow*140 + col + 4]);
    float y[8];
#pragma unroll
    for (int j = 0; j < 4; j++){ y[j] = b2f(lo[j]); y[4+j] = b2f(hi[j]); }
    if (addend){
      u16x8 ad = *(const u16x8*)(addend + gbase + col);
#pragma unroll
      for (int j = 0; j < 8; j++) y[j] += b2f(ad[j]);
    }
    if (bias){
#pragma unroll
      for (int j = 0; j < 8; j++) y[j] += bias[n0 + col + j];
    }
    if (bn_s){
#pragma unroll
      for (int j = 0; j < 8; j++){
        float t2 = y[j]*bn_s[n0 + col + j] + bn_t[n0 + col + j];
        y[j] = fmaxf(t2, 0.f);
      }
    }
    u16x8 o;
#pragma unroll
    for (int j = 0; j < 8; j++) o[j] = f2b(y[j]);
    *(u16x8*)(out + gbase + col) = o;
  }
}

// ---------------------------------------------------------------------------
// Per-WG 64x256x256 GEMM, 8 waves (512 thr): wave w owns n-cols w*32..+31
// (mt=4, nt=2). B-fragments streamed with a 2-fragment rolling window
// (low VGPR pressure; weights are L2-resident). A from swizzled LDS.
// ---------------------------------------------------------------------------
DEVINL void wg_gemm_reg(const unsigned short* __restrict__ Wt,
                        const char* Als, int tid, f32x4 (&acc)[4][2])
{
  const int lane = tid & 63;
  const int wave = tid >> 6;          // 0..7
  const int lrow = lane & 15, lq = lane >> 4;
  const unsigned short* base0 = Wt + (size_t)(wave*32 + lrow)*256 + lq*8;
  const unsigned short* base1 = base0 + 16*256;

  int rbase[4], rsw[4];
#pragma unroll
  for (int mt = 0; mt < 4; mt++){
    int row = mt*16 + lrow;
    rbase[mt] = row*512;
    rsw[mt]   = (row & 7) << 4;
  }

  bf16x8 bn0 = *(const bf16x8*)(base0);
  bf16x8 bn1 = *(const bf16x8*)(base1);
#pragma unroll
  for (int k = 0; k < 8; k++){
    bf16x8 b0 = bn0, b1 = bn1;
    if (k < 7){
      bn0 = *(const bf16x8*)(base0 + (k+1)*32);
      bn1 = *(const bf16x8*)(base1 + (k+1)*32);
    }
    bf16x8 af[4];
#pragma unroll
    for (int mt = 0; mt < 4; mt++)
      af[mt] = *(const bf16x8*)(Als + rbase[mt] + ((k*64 + lq*16) ^ rsw[mt]));
#pragma unroll
    for (int mt = 0; mt < 4; mt++){
      acc[mt][0] = __builtin_amdgcn_mfma_f32_16x16x32_bf16(af[mt], b0, acc[mt][0], 0, 0, 0);
      acc[mt][1] = __builtin_amdgcn_mfma_f32_16x16x32_bf16(af[mt], b1, acc[mt][1], 0, 0, 0);
    }
  }
}

// Epilogue with bias + fc residual from registers (BY REFERENCE — no decay).
DEVINL void wg_epi_fc(f32x4 (&acc)[4][2], char* Yls, const float* __restrict__ bias,
                      const float (&fc)[4][2][4], int tid)
{
  const int lane = tid & 63, wave = tid >> 6;
  const int lrow = lane & 15, lq = lane >> 4;
#pragma unroll
  for (int mt = 0; mt < 4; mt++){
#pragma unroll
    for (int nt = 0; nt < 2; nt++){
      const int col = wave*32 + nt*16 + lrow;
      const float bv = bias[col];
#pragma unroll
      for (int r = 0; r < 4; r++){
        const int row = mt*16 + lq*4 + r;
        float y = acc[mt][nt][r] + bv + fc[mt][nt][r];
        *(unsigned short*)(Yls + row*512 + ((col*2) ^ ((row & 7) << 4))) = f2b(y);
      }
    }
  }
  __syncthreads();
}

// Plain epilogue (no bias, no residual).
DEVINL void wg_epi_plain(f32x4 (&acc)[4][2], char* Yls, int tid)
{
  const int lane = tid & 63, wave = tid >> 6;
  const int lrow = lane & 15, lq = lane >> 4;
#pragma unroll
  for (int mt = 0; mt < 4; mt++){
#pragma unroll
    for (int nt = 0; nt < 2; nt++){
      const int col = wave*32 + nt*16 + lrow;
#pragma unroll
      for (int r = 0; r < 4; r++){
        const int row = mt*16 + lq*4 + r;
        *(unsigned short*)(Yls + row*512 + ((col*2) ^ ((row & 7) << 4))) = f2b(acc[mt][nt][r]);
      }
    }
  }
  __syncthreads();
}

// Epilogue into packed bf16 registers (no LDS, no barrier).
DEVINL void wg_epi_regs(f32x4 (&acc)[4][2], const float* __restrict__ bias,
                        const float (&fc)[4][2][4], unsigned int (&hp)[4][2][2],
                        int tid)
{
  const int lane = tid & 63, wave = tid >> 6;
  const int lrow = lane & 15;
#pragma unroll
  for (int mt = 0; mt < 4; mt++){
#pragma unroll
    for (int nt = 0; nt < 2; nt++){
      const int col = wave*32 + nt*16 + lrow;
      const float bv = bias[col];
#pragma unroll
      for (int p = 0; p < 2; p++){
        float y0 = acc[mt][nt][2*p]   + bv + fc[mt][nt][2*p];
        float y1 = acc[mt][nt][2*p+1] + bv + fc[mt][nt][2*p+1];
        hp[mt][nt][p] = (unsigned int)f2b(y0) | ((unsigned int)f2b(y1) << 16);
      }
    }
  }
}

// v epilogue: write TRANSPOSED VT[d][k] into swizzled [256][64] bf16 buffer.
DEVINL void wg_epi_vt(f32x4 (&acc)[4][2], char* VT, int tid)
{
  const int lane = tid & 63, wave = tid >> 6;
  const int lrow = lane & 15, lq = lane >> 4;
#pragma unroll
  for (int mt = 0; mt < 4; mt++){
#pragma unroll
    for (int nt = 0; nt < 2; nt++){
      const int col  = wave*32 + nt*16 + lrow;   // d: 0..255
      const int row0 = mt*16 + lq*4;             // k: 0..63
      u16x4 w;
#pragma unroll
      for (int r = 0; r < 4; r++) w[r] = f2b(acc[mt][nt][r]);
      *(u16x4*)(VT + col*128 + ((row0*2) ^ ((col & 7) << 4))) = w;
    }
  }
  __syncthreads();
}

// ---------------------------------------------------------------------------
// Fused transformer block, 2-buffer LDS plan (81216 B -> 2 WGs/CU).
//   fc preloaded ONCE into 32 VGPRs (dead after h_pos); h_pos in 16B of
//   packed bf16 regs; LN residual from regs; out written once, coalesced.
// Timeline:
//   fc->regs; H2->BA; h_geo=BA@m2w2+fc->BB; H1->BA; h_pos=BA@m1w2+fc->REGS;
//   q=BB@wq->BA; k=BB@wk->BB; S=q.k^T(regs)->softmax(regs)->Pm;
//   hp(regs)->BA; v=BA@wv->VT(BB); O=Pm@VT->BA; y=BA@wo(regs);
//   z=y+bo+hp(regs)->BA; LN rows from BA -> out.
// ---------------------------------------------------------------------------
template<int CS, bool F32IN>
__global__ __launch_bounds__(512, 4) void block_k(
    const float* __restrict__ pos,
    const float* __restrict__ featF,
    const unsigned short* __restrict__ featB,
    const float* __restrict__ w1a, const float* __restrict__ b1a,
    const float* __restrict__ w1b, const float* __restrict__ b1b,
    const unsigned short* __restrict__ m1w2T, const float* __restrict__ m1b2,
    const unsigned short* __restrict__ m2w2T, const float* __restrict__ m2b2,
    const unsigned short* __restrict__ wqT, const unsigned short* __restrict__ wkT,
    const unsigned short* __restrict__ wvT, const unsigned short* __restrict__ woT,
    const float* __restrict__ bo, const float* __restrict__ lgam,
    const float* __restrict__ lbet,
    unsigned short* __restrict__ out)
{
  __shared__ __attribute__((aligned(16))) char smem[81216];
  char* BA = smem;
  char* BB = smem + 32768;
  char* Pm = smem + 65536;                          // 8192 B
  float (*P3)[3]    = (float(*)[3])(smem + 73728);  // 768
  float (*Cg)[3]    = (float(*)[3])(smem + 74496);  // 48 (+pad)
  float (*Gg)[4]    = (float(*)[4])(smem + 74560);  // 1024
  float (*smx)[2]   = (float(*)[2])(smem + 75584);  // 512
  float (*ssm)[2]   = (float(*)[2])(smem + 76096);  // 512
  float (*sred)[8]  = (float(*)[8])(smem + 76608);  // 2048
  float (*s2red)[8] = (float(*)[8])(smem + 78656);  // 2048
  float* mub = (float*)(smem + 80704);              // 256
  float* rsb = (float*)(smem + 80960);              // 256 -> ends 81216

  const int tid  = threadIdx.x;
  const int lane = tid & 63;
  const int wave = tid >> 6;          // 0..7
  const int lrow = lane & 15, lq = lane >> 4;
  const int m0 = blockIdx.x * 64;

  unsigned short* gout = out + (size_t)m0 * 256;

  // ---- preload fc residual fragments into registers (latency hidden) ----
  float fcf[4][2][4];
  {
    const int col0 = wave*32 + lrow;
    if constexpr (F32IN){
      const float* resF = featF + (size_t)m0 * 256;
#pragma unroll
      for (int mt = 0; mt < 4; mt++)
#pragma unroll
        for (int nt = 0; nt < 2; nt++)
#pragma unroll
          for (int r = 0; r < 4; r++){
            int row = mt*16 + lq*4 + r, col = col0 + nt*16;
            fcf[mt][nt][r] = resF[row*256 + col];
          }
    } else {
      const unsigned short* resB = featB + (size_t)m0 * 256;
#pragma unroll
      for (int mt = 0; mt < 4; mt++)
#pragma unroll
        for (int nt = 0; nt < 2; nt++)
#pragma unroll
          for (int r = 0; r < 4; r++){
            int row = mt*16 + lq*4 + r, col = col0 + nt*16;
            fcf[mt][nt][r] = b2f(resB[row*256 + col]);
          }
    }
  }

  // ---- load pos ----
  if (tid < 64){
    P3[tid][0] = pos[(size_t)(m0+tid)*3 + 0];
    P3[tid][1] = pos[(size_t)(m0+tid)*3 + 1];
    P3[tid][2] = pos[(size_t)(m0+tid)*3 + 2];
  }
  __syncthreads();

  // ---- geometry ----
  constexpr int NCH = 64 / CS;
  if (tid < NCH*3){
    int ch = tid / 3, c = tid - ch*3;
    float s = 0.f;
    for (int r = 0; r < CS; r++) s += P3[ch*CS + r][c];
    Cg[ch][c] = s / (float)CS;
  }
  __syncthreads();
  if (tid < 64){
    int ch = (CS == 16) ? (tid >> 4) : 0;
    float x = P3[tid][0] - Cg[ch][0];
    float y = P3[tid][1] - Cg[ch][1];
    float z = P3[tid][2] - Cg[ch][2];
    Gg[tid][0] = x; Gg[tid][1] = y; Gg[tid][2] = z;
    Gg[tid][3] = sqrtf(x*x + y*y + z*z);
  }
  __syncthreads();

  // ---- H2 = relu(G @ w1b + b1b) -> BA ----  (avg branch == 0 exactly)
  {
    const int c = tid & 255;
    const int r0 = (tid >> 8) * 32;
    const float wb0 = w1b[768+c], wb1 = w1b[1024+c], wb2 = w1b[1280+c];
    const float bb  = b1b[c];
    for (int r = r0; r < r0 + 32; r++){
      float v2 = bb + Gg[r][0]*wb0 + Gg[r][1]*wb1 + Gg[r][2]*wb2;
      *(unsigned short*)(BA + r*512 + ((c*2) ^ ((r & 7) << 4))) = f2b(fmaxf(v2, 0.f));
    }
  }
  __syncthreads();
  // h_geo = fc(regs) + H2 @ m2w2 + b -> BB
  {
    f32x4 acc[4][2] = {};
    wg_gemm_reg(m2w2T, BA, tid, acc);
    wg_epi_fc(acc, BB, m2b2, fcf, tid);
  }
  // ---- H1 = relu(G @ w1a + b1a) -> BA ----
  {
    const int c = tid & 255;
    const int r0 = (tid >> 8) * 32;
    const float wa0 = w1a[c], wa1 = w1a[256+c], wa2 = w1a[512+c], wa3 = w1a[768+c];
    const float ba  = b1a[c];
    for (int r = r0; r < r0 + 32; r++){
      float v1 = ba + Gg[r][0]*wa0 + Gg[r][1]*wa1 + Gg[r][2]*wa2 + Gg[r][3]*wa3;
      *(unsigned short*)(BA + r*512 + ((c*2) ^ ((r & 7) << 4))) = f2b(fmaxf(v1, 0.f));
    }
  }
  __syncthreads();
  // h_pos = fc(regs) + H1 @ m1w2 + b -> REGISTERS (packed bf16); fcf dies here
  unsigned int hp[4][2][2];
  {
    f32x4 acc[4][2] = {};
    wg_gemm_reg(m1w2T, BA, tid, acc);
    wg_epi_regs(acc, m1b2, fcf, hp, tid);
    __syncthreads();                     // all A-reads of BA done
  }
  // q = h_geo @ wq(/16) -> BA
  {
    f32x4 acc[4][2] = {};
    wg_gemm_reg(wqT, BB, tid, acc);
    wg_epi_plain(acc, BA, tid);
  }
  // k = h_geo @ wk -> BB in place
  {
    f32x4 acc[4][2] = {};
    wg_gemm_reg(wkT, BB, tid, acc);
    __syncthreads();                     // all A-reads of BB done
    wg_epi_plain(acc, BB, tid);
  }

  // ---- S = q k^T in registers, softmax in registers -> Pm (bf16) ----
  if (CS == 64){
    const int tr = wave & 3, tc0 = wave >> 2;   // tiles (tr,tc0) and (tr,tc0+2)
    f32x4 sacc[2] = {};
    const int qrow = tr*16 + lrow;
    const int qsw  = (qrow & 7) << 4;
#pragma unroll
    for (int kk = 0; kk < 8; kk++){
      bf16x8 aq = *(const bf16x8*)(BA + qrow*512 + ((kk*64 + lq*16) ^ qsw));
#pragma unroll
      for (int c = 0; c < 2; c++){
        int brow = tc0*16 + c*32 + lrow;
        bf16x8 bk = *(const bf16x8*)(BB + brow*512 + ((kk*64 + lq*16) ^ ((brow & 7) << 4)));
        sacc[c] = __builtin_amdgcn_mfma_f32_16x16x32_bf16(aq, bk, sacc[c], 0, 0, 0);
      }
    }
    // per-row partial max & expsum across the 16-lane lrow group
    float fmx[4], fsm[4];
#pragma unroll
    for (int r = 0; r < 4; r++){
      float m = fmaxf(sacc[0][r], sacc[1][r]);
#pragma unroll
      for (int d = 1; d < 16; d <<= 1) m = fmaxf(m, __shfl_xor(m, d));
      float e0 = __expf(sacc[0][r] - m);
      float e1 = __expf(sacc[1][r] - m);
      sacc[0][r] = e0; sacc[1][r] = e1;
      float s = e0 + e1;
#pragma unroll
      for (int d = 1; d < 16; d <<= 1) s += __shfl_xor(s, d);
      fmx[r] = m; fsm[r] = s;
    }
    if (lrow == 0){
#pragma unroll
      for (int r = 0; r < 4; r++){
        int row = tr*16 + lq*4 + r;
        smx[row][tc0] = fmx[r];
        ssm[row][tc0] = fsm[r];
      }
    }
    __syncthreads();
#pragma unroll
    for (int r = 0; r < 4; r++){
      int row = tr*16 + lq*4 + r;
      float m0v = smx[row][0], m1v = smx[row][1];
      float M = fmaxf(m0v, m1v);
      float S = ssm[row][0]*__expf(m0v - M) + ssm[row][1]*__expf(m1v - M);
      float f = __expf((tc0 ? m1v : m0v) - M) / S;
      int sw = (row & 7) << 4;
#pragma unroll
      for (int c = 0; c < 2; c++){
        int col = tc0*16 + c*32 + lrow;
        *(unsigned short*)(Pm + row*128 + ((col*2) ^ sw)) = f2b(sacc[c][r]*f);
      }
    }
    __syncthreads();
  } else {
    if (wave < 4){
      f32x4 sacc = {};
      const int qrow = wave*16 + lrow;
      const int qsw  = (qrow & 7) << 4;
#pragma unroll
      for (int kk = 0; kk < 8; kk++){
        bf16x8 aq = *(const bf16x8*)(BA + qrow*512 + ((kk*64 + lq*16) ^ qsw));
        bf16x8 bk = *(const bf16x8*)(BB + qrow*512 + ((kk*64 + lq*16) ^ qsw));
        sacc = __builtin_amdgcn_mfma_f32_16x16x32_bf16(aq, bk, sacc, 0, 0, 0);
      }
#pragma unroll
      for (int r = 0; r < 4; r++){
        float m = sacc[r];
#pragma unroll
        for (int d = 1; d < 16; d <<= 1) m = fmaxf(m, __shfl_xor(m, d));
        float e = __expf(sacc[r] - m);
        float s = e;
#pragma unroll
        for (int d = 1; d < 16; d <<= 1) s += __shfl_xor(s, d);
        int row = wave*16 + lq*4 + r;
        *(unsigned short*)(Pm + row*64 + ((lrow*2) ^ ((row & 3) << 4))) = f2b(e / s);
      }
    } else {
      int t2 = tid - 256;            // 0..255: zero-pad P cols 16..31
      int row = t2 >> 2, j = t2 & 3;
      u16x4 z = {};
      *(u16x4*)(Pm + row*64 + ((32 + j*8) ^ ((row & 3) << 4))) = z;
    }
    __syncthreads();
  }

  // ---- h_pos regs -> BA (q dead); v = h_pos @ wv -> VT (BB) ----
  {
    const int col0 = wave*32 + lrow;
#pragma unroll
    for (int mt = 0; mt < 4; mt++)
#pragma unroll
      for (int nt = 0; nt < 2; nt++)
#pragma unroll
        for (int p = 0; p < 2; p++){
          int col = col0 + nt*16;
          int row0 = mt*16 + lq*4 + 2*p;
          unsigned int d = hp[mt][nt][p];
          *(unsigned short*)(BA + row0*512 + ((col*2) ^ ((row0 & 7) << 4))) = (unsigned short)d;
          int row1 = row0 + 1;
          *(unsigned short*)(BA + row1*512 + ((col*2) ^ ((row1 & 7) << 4))) = (unsigned short)(d >> 16);
        }
  }
  __syncthreads();
  {
    f32x4 acc[4][2] = {};
    wg_gemm_reg(wvT, BA, tid, acc);
    wg_epi_vt(acc, BB, tid);             // k (BB) dead since S-phase sync
  }

  // ---- O = P @ V -> BA (h_pos LDS copy dead after v-GEMM) ----
  {
    f32x4 oacc[4][2] = {};
    const int dbase = wave * 32;
    if (CS == 64){
#pragma unroll
      for (int kk = 0; kk < 2; kk++){
        bf16x8 ap[4];
#pragma unroll
        for (int mt = 0; mt < 4; mt++){
          int row = mt*16 + lrow;
          ap[mt] = *(const bf16x8*)(Pm + row*128 + ((kk*64 + lq*16) ^ ((row & 7) << 4)));
        }
#pragma unroll
        for (int nt = 0; nt < 2; nt++){
          const int d = dbase + nt*16 + lrow;
          bf16x8 bv = *(const bf16x8*)(BB + d*128 + ((kk*64 + lq*16) ^ ((d & 7) << 4)));
#pragma unroll
          for (int mt = 0; mt < 4; mt++)
            oacc[mt][nt] = __builtin_amdgcn_mfma_f32_16x16x32_bf16(ap[mt], bv, oacc[mt][nt], 0, 0, 0);
        }
      }
    } else {
#pragma unroll
      for (int mt = 0; mt < 4; mt++){
        int row = mt*16 + lrow;
        bf16x8 ap = *(const bf16x8*)(Pm + row*64 + ((lq*16) ^ ((row & 3) << 4)));
#pragma unroll
        for (int nt = 0; nt < 2; nt++){
          const int d = dbase + nt*16 + lrow;
          bf16x8 bv = *(const bf16x8*)(BB + d*128 + ((mt*32 + (lq & 1)*16) ^ ((d & 7) << 4)));
          oacc[mt][nt] = __builtin_amdgcn_mfma_f32_16x16x32_bf16(ap, bv, oacc[mt][nt], 0, 0, 0);
        }
      }
    }
    // BA reads all finished at epi_vt's barrier; safe to overwrite.
#pragma unroll
    for (int mt = 0; mt < 4; mt++){
#pragma unroll
      for (int nt = 0; nt < 2; nt++){
#pragma unroll
        for (int r = 0; r < 4; r++){
          int row = mt*16 + lq*4 + r;
          int col = dbase + nt*16 + lrow;
          *(unsigned short*)(BA + row*512 + ((col*2) ^ ((row & 7) << 4))) = f2b(oacc[mt][nt][r]);
        }
      }
    }
    __syncthreads();
  }

  // ---- y = O @ wo (regs); z = y + bo + hp(regs) -> BA; LN -> out ----
  {
    f32x4 yacc[4][2] = {};
    wg_gemm_reg(woT, BA, tid, yacc);
    __syncthreads();                     // all O-reads of BA done
    const int col0 = wave*32 + lrow;
#pragma unroll
    for (int mt = 0; mt < 4; mt++){
#pragma unroll
      for (int nt = 0; nt < 2; nt++){
        const int col = col0 + nt*16;
        const float bov = bo[col];
#pragma unroll
        for (int p = 0; p < 2; p++){
          unsigned int d = hp[mt][nt][p];
          int row0 = mt*16 + lq*4 + 2*p;
          float z0 = yacc[mt][nt][2*p]   + bov + b2f((unsigned short)d);
          float z1 = yacc[mt][nt][2*p+1] + bov + b2f((unsigned short)(d >> 16));
          *(unsigned short*)(BA + row0*512 + ((col*2) ^ ((row0 & 7) << 4))) = f2b(z0);
          int row1 = row0 + 1;
          *(unsigned short*)(BA + row1*512 + ((col*2) ^ ((row1 & 7) << 4))) = f2b(z1);
        }
      }
    }
    __syncthreads();
  }
  {
    const int row = tid >> 3, part = tid & 7;
    const size_t gr = (size_t)row * 256;
    const int sw = (row & 7) << 4;
    float sm = 0.f, sq = 0.f;
#pragma unroll
    for (int i = 0; i < 4; i++){
      int col = part*32 + i*8;
      u16x8 v = *(const u16x8*)(BA + row*512 + ((col*2) ^ sw));
#pragma unroll
      for (int j = 0; j < 8; j++){
        float y = b2f(v[j]);
        sm += y; sq += y*y;
      }
    }
    sred[row][part] = sm; s2red[row][part] = sq;
    __syncthreads();
    if (tid < 64){
      float s = 0.f, q2 = 0.f;
#pragma unroll
      for (int p = 0; p < 8; p++){ s += sred[tid][p]; q2 += s2red[tid][p]; }
      float mu = s * (1.0f/256.0f);
      float var = q2 * (1.0f/256.0f) - mu*mu;
      mub[tid] = mu;
      rsb[tid] = rsqrtf(var + 1e-5f);
    }
    __syncthreads();
    const float mu = mub[row], rs = rsb[row];
#pragma unroll
    for (int i = 0; i < 4; i++){
      int col = part*32 + i*8;
      u16x8 v = *(const u16x8*)(BA + row*512 + ((col*2) ^ sw));
      u16x8 o;
#pragma unroll
      for (int j = 0; j < 8; j++)
        o[j] = f2b((b2f(v[j]) - mu)*rs*lgam[col + j] + lbet[col + j]);
      *(u16x8*)(gout + gr + col) = o;
    }
  }
}

// ---------------------------------------------------------------------------
// Output: pos_ds gather + KNN max-pool.
// ---------------------------------------------------------------------------
__global__ __launch_bounds__(256) void out_k(
    const unsigned short* __restrict__ F2,
    const float* __restrict__ pos,
    const int* __restrict__ fps,
    const int* __restrict__ knn,
    float* __restrict__ outp)
{
  const int p = blockIdx.x;
  const int b = p >> 11;
  const int t = threadIdx.x;
  const int* kn = knn + (size_t)p * 16;
  const int c = t * 2;
  float m1 = -3.0e38f, m2 = -3.0e38f;
  for (int j = 0; j < 16; j++){
    int idx = kn[j];
    size_t row = ((size_t)b * 8192 + idx) * 512;
    u16x2 v = *(const u16x2*)(F2 + row + c);
    m1 = fmaxf(m1, b2f(v.x));
    m2 = fmaxf(m2, b2f(v.y));
  }
  float* of = outp + 49152 + (size_t)p * 512 + c;
  float2 o; o.x = m1; o.y = m2;
  *(float2*)of = o;
  if (t < 3){
    int fi = fps[p];
    outp[(size_t)p*3 + t] = pos[((size_t)b*8192 + fi)*3 + t];
  }
}

// ---------------------------------------------------------------------------
extern "C" void kernel_launch(void* const* d_in, const int* in_sizes, int n_in,
                              void* d_out, int out_size, void* d_ws, size_t ws_size,
                              hipStream_t stream)
{
  (void)in_sizes; (void)n_in; (void)out_size; (void)ws_size;

  const float* pos  = (const float*)d_in[0];
  const float* feat = (const float*)d_in[1];
  const int*   fps  = (const int*)d_in[2];
  const int*   knn  = (const int*)d_in[3];
  const float* m1w1 = (const float*)d_in[6];
  const float* m1b1 = (const float*)d_in[7];
  const float* m1w2 = (const float*)d_in[8];
  const float* m1b2 = (const float*)d_in[9];
  const float* m2w1 = (const float*)d_in[10];
  const float* m2b1 = (const float*)d_in[11];
  const float* m2w2 = (const float*)d_in[12];
  const float* m2b2 = (const float*)d_in[13];
  const float* wq   = (const float*)d_in[14];
  const float* wk   = (const float*)d_in[15];
  const float* wv   = (const float*)d_in[16];
  const float* wo   = (const float*)d_in[17];
  const float* bo   = (const float*)d_in[18];
  const float* lng  = (const float*)d_in[19];
  const float* lnb  = (const float*)d_in[20];
  const float* tdw  = (const float*)d_in[21];
  const float* tdb  = (const float*)d_in[22];
  const float* bng  = (const float*)d_in[23];
  const float* bnb  = (const float*)d_in[24];
  const float* bnm  = (const float*)d_in[25];
  const float* bnv  = (const float*)d_in[26];

  char* ws = (char*)d_ws;
  unsigned short* wT = (unsigned short*)ws;
  float* bns = (float*)(ws + 1835008);
  float* bnt = (float*)(ws + 1837056);
  const size_t SLOT = 33554432;
  unsigned short* A  = (unsigned short*)(ws + 2097152);
  unsigned short* Bs = (unsigned short*)(ws + 2097152 + SLOT);
  unsigned short* E  = (unsigned short*)(ws + 2097152 + 2*SLOT);

  auto wtm = [&](int mat, int i){ return wT + (size_t)mat*131072 + (size_t)i*65536; };
  unsigned short* tdT = wT + 786432;

  prep_k<<<3586, 256, 0, stream>>>(m1w2, m2w2, wq, wk, wv, wo, tdw, tdb, bng, bnb, bnm, bnv,
                                   wT, bns, bnt);

  block_k<16, true><<<1024, 512, 0, stream>>>(
      pos, feat, nullptr,
      m1w1, m1b1, m2w1, m2b1,
      wtm(0,0), m1b2, wtm(1,0), m2b2,
      wtm(2,0), wtm(3,0), wtm(4,0), wtm(5,0),
      bo, lng, lnb, A);

  block_k<64, false><<<1024, 512, 0, stream>>>(
      pos, nullptr, A,
      m1w1 + 1024, m1b1 + 256, m2w1 + 1536, m2b1 + 256,
      wtm(0,1), m1b2 + 256, wtm(1,1), m2b2 + 256,
      wtm(2,1), wtm(3,1), wtm(4,1), wtm(5,1),
      bo + 256, lng + 256, lnb + 256, Bs);

  gemm_k<<<dim3(512,4), 256, 0, stream>>>(Bs, tdT, E, nullptr, nullptr, bns, bnt, 512);

  out_k<<<16384, 256, 0, stream>>>(E, pos, fps, knn, (float*)d_out);
}

// Round 5
// 565.380 us; speedup vs baseline: 1.3169x; 1.3169x over previous
//
#include <hip/hip_runtime.h>
#include <stdint.h>
#include <stddef.h>

typedef __attribute__((ext_vector_type(8))) short bf16x8;
typedef __attribute__((ext_vector_type(4))) float f32x4;
typedef __attribute__((ext_vector_type(8))) unsigned short u16x8;
typedef __attribute__((ext_vector_type(4))) unsigned short u16x4;
typedef __attribute__((ext_vector_type(2))) unsigned short u16x2;

#define DEVINL __device__ __forceinline__

DEVINL unsigned short f2b(float x){
  union { float f; unsigned int u; } v; v.f = x;
  return (unsigned short)((v.u + 0x7FFFu + ((v.u >> 16) & 1u)) >> 16);
}
DEVINL float b2f(unsigned short h){
  union { float f; unsigned int u; } v; v.u = ((unsigned int)h) << 16;
  return v.f;
}

DEVINL void gl_lds16(void* g, void* lds){
  __builtin_amdgcn_global_load_lds(
      (__attribute__((address_space(1))) void*)g,
      (__attribute__((address_space(3))) void*)lds, 16, 0, 0);
}

// ---------------------------------------------------------------------------
// prep: transpose+cast weights to bf16 [n][k]; fold 1/16 into wq; fold BN.
// ---------------------------------------------------------------------------
__global__ __launch_bounds__(256) void prep_k(
    const float* __restrict__ m1w2, const float* __restrict__ m2w2,
    const float* __restrict__ wqp,  const float* __restrict__ wkp,
    const float* __restrict__ wvp,  const float* __restrict__ wop,
    const float* __restrict__ tdw,  const float* __restrict__ tdb,
    const float* __restrict__ bng,  const float* __restrict__ bnb,
    const float* __restrict__ bnm,  const float* __restrict__ bnv,
    unsigned short* __restrict__ wT, float* __restrict__ bns, float* __restrict__ bnt)
{
  int idx = blockIdx.x * 256 + threadIdx.x;
  if (idx < 786432){
    int mat = idx >> 17;
    int e   = idx & 131071;
    int i   = e >> 16;
    int eb  = e & 65535;
    int n = eb >> 8, kx = eb & 255;
    const float* src; float sc = 1.0f;
    if      (mat == 0) src = m1w2;
    else if (mat == 1) src = m2w2;
    else if (mat == 2){ src = wqp; sc = 0.0625f; }
    else if (mat == 3) src = wkp;
    else if (mat == 4) src = wvp;
    else               src = wop;
    wT[idx] = f2b(src[i*65536 + kx*256 + n] * sc);
  } else if (idx < 917504){
    int e = idx - 786432;
    int n = e >> 8, kx = e & 255;
    wT[786432 + e] = f2b(tdw[kx*512 + n]);
  } else if (idx < 918016){
    int c = idx - 917504;
    float s = bng[c] * rsqrtf(bnv[c] + 1e-5f);
    bns[c] = s;
    bnt[c] = (tdb[c] - bnm[c]) * s + bnb[c];
  }
}

// ---------------------------------------------------------------------------
// Generic GEMM (m97-style), used only for the final td+BN (N=512).
// ---------------------------------------------------------------------------
__global__ __launch_bounds__(256) void gemm_k(
    const unsigned short* __restrict__ A,
    const unsigned short* __restrict__ Wt,
    unsigned short* __restrict__ out,
    const float* __restrict__ bias,
    const unsigned short* __restrict__ addend,
    const float* __restrict__ bn_s,
    const float* __restrict__ bn_t,
    int ldc)
{
  __shared__ __attribute__((aligned(16))) unsigned short aT[512*8];
  __shared__ __attribute__((aligned(16))) unsigned short bT[512*8];
  __shared__ __attribute__((aligned(16))) unsigned short epi[128*140];

  const int tid  = threadIdx.x;
  const int lane = tid & 63;
  const int wave = tid >> 6;
  const int lrow = lane & 15, lq = lane >> 4;
  const int wr = wave >> 1, wc = wave & 1;
  const int m0 = blockIdx.x * 128;
  const int n0 = blockIdx.y * 128;

  f32x4 acc[4][4] = {};

  int aOff[4], bOff[4];
#pragma unroll
  for (int mt = 0; mt < 4; mt++){
    int row = wr*64 + mt*16 + lrow;
    aOff[mt] = row*64 + ((lq ^ ((row >> 1) & 3)) << 4);
  }
#pragma unroll
  for (int nt = 0; nt < 4; nt++){
    int row = wc*64 + nt*16 + lrow;
    bOff[nt] = row*64 + ((lq ^ ((row >> 1) & 3)) << 4);
  }

  const int s0 = tid, s1 = tid + 256;
  const int r0 = s0 >> 2, kc0 = (s0 & 3) ^ ((r0 >> 1) & 3);
  const int r1 = s1 >> 2, kc1 = (s1 & 3) ^ ((r1 >> 1) & 3);
  const unsigned short* Ab = A  + (size_t)m0 * 256;
  const unsigned short* Bb = Wt + (size_t)n0 * 256;
  char* aL = (char*)aT;
  char* bL = (char*)bT;
  const int wslot = wave * 64 * 16;

  for (int k0 = 0; k0 < 256; k0 += 32){
    __syncthreads();
    gl_lds16((void*)(Ab + r0*256 + k0 + kc0*8), aL + wslot);
    gl_lds16((void*)(Ab + r1*256 + k0 + kc1*8), aL + 4096 + wslot);
    gl_lds16((void*)(Bb + r0*256 + k0 + kc0*8), bL + wslot);
    gl_lds16((void*)(Bb + r1*256 + k0 + kc1*8), bL + 4096 + wslot);
    __syncthreads();
    bf16x8 af[4], bfr[4];
#pragma unroll
    for (int mt = 0; mt < 4; mt++) af[mt]  = *(const bf16x8*)(aL + aOff[mt]);
#pragma unroll
    for (int nt = 0; nt < 4; nt++) bfr[nt] = *(const bf16x8*)(bL + bOff[nt]);
#pragma unroll
    for (int mt = 0; mt < 4; mt++)
#pragma unroll
      for (int nt = 0; nt < 4; nt++)
        acc[mt][nt] = __builtin_amdgcn_mfma_f32_16x16x32_bf16(af[mt], bfr[nt], acc[mt][nt], 0, 0, 0);
  }

  __syncthreads();
#pragma unroll
  for (int mt = 0; mt < 4; mt++){
    int row = wr*64 + mt*16 + lq*4;
#pragma unroll
    for (int nt = 0; nt < 4; nt++){
      int col = wc*64 + nt*16 + lrow;
#pragma unroll
      for (int r = 0; r < 4; r++)
        epi[(row + r)*140 + col] = f2b(acc[mt][nt][r]);
    }
  }
  __syncthreads();

  const int erow = tid >> 1, h = tid & 1;
  const size_t gbase = (size_t)(m0 + erow) * (size_t)ldc + n0;
#pragma unroll
  for (int i = 0; i < 8; i++){
    int col = h*64 + i*8;
    u16x4 lo = *(const u16x4*)(&epi[erow*140 + col]);
    u16x4 hi = *(const u16x4*)(&epi[erow*140 + col + 4]);
    float y[8];
#pragma unroll
    for (int j = 0; j < 4; j++){ y[j] = b2f(lo[j]); y[4+j] = b2f(hi[j]); }
    if (addend){
      u16x8 ad = *(const u16x8*)(addend + gbase + col);
#pragma unroll
      for (int j = 0; j < 8; j++) y[j] += b2f(ad[j]);
    }
    if (bias){
#pragma unroll
      for (int j = 0; j < 8; j++) y[j] += bias[n0 + col + j];
    }
    if (bn_s){
#pragma unroll
      for (int j = 0; j < 8; j++){
        float t2 = y[j]*bn_s[n0 + col + j] + bn_t[n0 + col + j];
        y[j] = fmaxf(t2, 0.f);
      }
    }
    u16x8 o;
#pragma unroll
    for (int j = 0; j < 8; j++) o[j] = f2b(y[j]);
    *(u16x8*)(out + gbase + col) = o;
  }
}

// ---------------------------------------------------------------------------
// Per-WG 64x256x256 GEMM, 8 waves (512 thr): wave w owns n-cols w*32..+31
// (mt=4, nt=2). B-fragments streamed with a 2-fragment rolling window
// (low VGPR pressure; weights are L2-resident). A from swizzled LDS.
// ---------------------------------------------------------------------------
DEVINL void wg_gemm_reg(const unsigned short* __restrict__ Wt,
                        const char* Als, int tid, f32x4 (&acc)[4][2])
{
  const int lane = tid & 63;
  const int wave = tid >> 6;          // 0..7
  const int lrow = lane & 15, lq = lane >> 4;
  const unsigned short* base0 = Wt + (size_t)(wave*32 + lrow)*256 + lq*8;
  const unsigned short* base1 = base0 + 16*256;

  int rbase[4], rsw[4];
#pragma unroll
  for (int mt = 0; mt < 4; mt++){
    int row = mt*16 + lrow;
    rbase[mt] = row*512;
    rsw[mt]   = (row & 7) << 4;
  }

  bf16x8 bn0 = *(const bf16x8*)(base0);
  bf16x8 bn1 = *(const bf16x8*)(base1);
#pragma unroll
  for (int k = 0; k < 8; k++){
    bf16x8 b0 = bn0, b1 = bn1;
    if (k < 7){
      bn0 = *(const bf16x8*)(base0 + (k+1)*32);
      bn1 = *(const bf16x8*)(base1 + (k+1)*32);
    }
    bf16x8 af[4];
#pragma unroll
    for (int mt = 0; mt < 4; mt++)
      af[mt] = *(const bf16x8*)(Als + rbase[mt] + ((k*64 + lq*16) ^ rsw[mt]));
#pragma unroll
    for (int mt = 0; mt < 4; mt++){
      acc[mt][0] = __builtin_amdgcn_mfma_f32_16x16x32_bf16(af[mt], b0, acc[mt][0], 0, 0, 0);
      acc[mt][1] = __builtin_amdgcn_mfma_f32_16x16x32_bf16(af[mt], b1, acc[mt][1], 0, 0, 0);
    }
  }
}

// Epilogue with bias + fc residual from registers (BY REFERENCE — no decay).
DEVINL void wg_epi_fc(f32x4 (&acc)[4][2], char* Yls, const float* __restrict__ bias,
                      const float (&fc)[4][2][4], int tid)
{
  const int lane = tid & 63, wave = tid >> 6;
  const int lrow = lane & 15, lq = lane >> 4;
#pragma unroll
  for (int mt = 0; mt < 4; mt++){
#pragma unroll
    for (int nt = 0; nt < 2; nt++){
      const int col = wave*32 + nt*16 + lrow;
      const float bv = bias[col];
#pragma unroll
      for (int r = 0; r < 4; r++){
        const int row = mt*16 + lq*4 + r;
        float y = acc[mt][nt][r] + bv + fc[mt][nt][r];
        *(unsigned short*)(Yls + row*512 + ((col*2) ^ ((row & 7) << 4))) = f2b(y);
      }
    }
  }
  __syncthreads();
}

// Plain epilogue (no bias, no residual).
DEVINL void wg_epi_plain(f32x4 (&acc)[4][2], char* Yls, int tid)
{
  const int lane = tid & 63, wave = tid >> 6;
  const int lrow = lane & 15, lq = lane >> 4;
#pragma unroll
  for (int mt = 0; mt < 4; mt++){
#pragma unroll
    for (int nt = 0; nt < 2; nt++){
      const int col = wave*32 + nt*16 + lrow;
#pragma unroll
      for (int r = 0; r < 4; r++){
        const int row = mt*16 + lq*4 + r;
        *(unsigned short*)(Yls + row*512 + ((col*2) ^ ((row & 7) << 4))) = f2b(acc[mt][nt][r]);
      }
    }
  }
  __syncthreads();
}

// Epilogue into packed bf16 registers (no LDS, no barrier).
DEVINL void wg_epi_regs(f32x4 (&acc)[4][2], const float* __restrict__ bias,
                        const float (&fc)[4][2][4], unsigned int (&hp)[4][2][2],
                        int tid)
{
  const int lane = tid & 63, wave = tid >> 6;
  const int lrow = lane & 15;
#pragma unroll
  for (int mt = 0; mt < 4; mt++){
#pragma unroll
    for (int nt = 0; nt < 2; nt++){
      const int col = wave*32 + nt*16 + lrow;
      const float bv = bias[col];
#pragma unroll
      for (int p = 0; p < 2; p++){
        float y0 = acc[mt][nt][2*p]   + bv + fc[mt][nt][2*p];
        float y1 = acc[mt][nt][2*p+1] + bv + fc[mt][nt][2*p+1];
        hp[mt][nt][p] = (unsigned int)f2b(y0) | ((unsigned int)f2b(y1) << 16);
      }
    }
  }
}

// v epilogue: write TRANSPOSED VT[d][k] into swizzled [256][64] bf16 buffer.
DEVINL void wg_epi_vt(f32x4 (&acc)[4][2], char* VT, int tid)
{
  const int lane = tid & 63, wave = tid >> 6;
  const int lrow = lane & 15, lq = lane >> 4;
#pragma unroll
  for (int mt = 0; mt < 4; mt++){
#pragma unroll
    for (int nt = 0; nt < 2; nt++){
      const int col  = wave*32 + nt*16 + lrow;   // d: 0..255
      const int row0 = mt*16 + lq*4;             // k: 0..63
      u16x4 w;
#pragma unroll
      for (int r = 0; r < 4; r++) w[r] = f2b(acc[mt][nt][r]);
      *(u16x4*)(VT + col*128 + ((row0*2) ^ ((col & 7) << 4))) = w;
    }
  }
  __syncthreads();
}

// ---------------------------------------------------------------------------
// Fused transformer block, 2-buffer LDS plan (81216 B -> 2 WGs/CU).
//   __launch_bounds__(512, 2): 2 WGs/CU target -> 128-VGPR ceiling.
//   (512,4) in prior rounds forced a 64-VGPR cap and spilled fcf/hp to
//   scratch (~230 MB of WRITE traffic, VGPR_Count pinned at 64).
//   fc preloaded ONCE into 32 VGPRs (dead after h_pos); h_pos in 16B of
//   packed bf16 regs; LN residual from regs; out written once, coalesced.
// Timeline:
//   fc->regs; H2->BA; h_geo=BA@m2w2+fc->BB; H1->BA; h_pos=BA@m1w2+fc->REGS;
//   q=BB@wq->BA; k=BB@wk->BB; S=q.k^T(regs)->softmax(regs)->Pm;
//   hp(regs)->BA; v=BA@wv->VT(BB); O=Pm@VT->BA; y=BA@wo(regs);
//   z=y+bo+hp(regs)->BA; LN rows from BA -> out.
// ---------------------------------------------------------------------------
template<int CS, bool F32IN>
__global__ __launch_bounds__(512, 2) void block_k(
    const float* __restrict__ pos,
    const float* __restrict__ featF,
    const unsigned short* __restrict__ featB,
    const float* __restrict__ w1a, const float* __restrict__ b1a,
    const float* __restrict__ w1b, const float* __restrict__ b1b,
    const unsigned short* __restrict__ m1w2T, const float* __restrict__ m1b2,
    const unsigned short* __restrict__ m2w2T, const float* __restrict__ m2b2,
    const unsigned short* __restrict__ wqT, const unsigned short* __restrict__ wkT,
    const unsigned short* __restrict__ wvT, const unsigned short* __restrict__ woT,
    const float* __restrict__ bo, const float* __restrict__ lgam,
    const float* __restrict__ lbet,
    unsigned short* __restrict__ out)
{
  __shared__ __attribute__((aligned(16))) char smem[81216];
  char* BA = smem;
  char* BB = smem + 32768;
  char* Pm = smem + 65536;                          // 8192 B
  float (*P3)[3]    = (float(*)[3])(smem + 73728);  // 768
  float (*Cg)[3]    = (float(*)[3])(smem + 74496);  // 48 (+pad)
  float (*Gg)[4]    = (float(*)[4])(smem + 74560);  // 1024
  float (*smx)[2]   = (float(*)[2])(smem + 75584);  // 512
  float (*ssm)[2]   = (float(*)[2])(smem + 76096);  // 512
  float (*sred)[8]  = (float(*)[8])(smem + 76608);  // 2048
  float (*s2red)[8] = (float(*)[8])(smem + 78656);  // 2048
  float* mub = (float*)(smem + 80704);              // 256
  float* rsb = (float*)(smem + 80960);              // 256 -> ends 81216

  const int tid  = threadIdx.x;
  const int lane = tid & 63;
  const int wave = tid >> 6;          // 0..7
  const int lrow = lane & 15, lq = lane >> 4;
  const int m0 = blockIdx.x * 64;

  unsigned short* gout = out + (size_t)m0 * 256;

  // ---- preload fc residual fragments into registers (latency hidden) ----
  float fcf[4][2][4];
  {
    const int col0 = wave*32 + lrow;
    if constexpr (F32IN){
      const float* resF = featF + (size_t)m0 * 256;
#pragma unroll
      for (int mt = 0; mt < 4; mt++)
#pragma unroll
        for (int nt = 0; nt < 2; nt++)
#pragma unroll
          for (int r = 0; r < 4; r++){
            int row = mt*16 + lq*4 + r, col = col0 + nt*16;
            fcf[mt][nt][r] = resF[row*256 + col];
          }
    } else {
      const unsigned short* resB = featB + (size_t)m0 * 256;
#pragma unroll
      for (int mt = 0; mt < 4; mt++)
#pragma unroll
        for (int nt = 0; nt < 2; nt++)
#pragma unroll
          for (int r = 0; r < 4; r++){
            int row = mt*16 + lq*4 + r, col = col0 + nt*16;
            fcf[mt][nt][r] = b2f(resB[row*256 + col]);
          }
    }
  }

  // ---- load pos ----
  if (tid < 64){
    P3[tid][0] = pos[(size_t)(m0+tid)*3 + 0];
    P3[tid][1] = pos[(size_t)(m0+tid)*3 + 1];
    P3[tid][2] = pos[(size_t)(m0+tid)*3 + 2];
  }
  __syncthreads();

  // ---- geometry ----
  constexpr int NCH = 64 / CS;
  if (tid < NCH*3){
    int ch = tid / 3, c = tid - ch*3;
    float s = 0.f;
    for (int r = 0; r < CS; r++) s += P3[ch*CS + r][c];
    Cg[ch][c] = s / (float)CS;
  }
  __syncthreads();
  if (tid < 64){
    int ch = (CS == 16) ? (tid >> 4) : 0;
    float x = P3[tid][0] - Cg[ch][0];
    float y = P3[tid][1] - Cg[ch][1];
    float z = P3[tid][2] - Cg[ch][2];
    Gg[tid][0] = x; Gg[tid][1] = y; Gg[tid][2] = z;
    Gg[tid][3] = sqrtf(x*x + y*y + z*z);
  }
  __syncthreads();

  // ---- H2 = relu(G @ w1b + b1b) -> BA ----  (avg branch == 0 exactly)
  {
    const int c = tid & 255;
    const int r0 = (tid >> 8) * 32;
    const float wb0 = w1b[768+c], wb1 = w1b[1024+c], wb2 = w1b[1280+c];
    const float bb  = b1b[c];
    for (int r = r0; r < r0 + 32; r++){
      float v2 = bb + Gg[r][0]*wb0 + Gg[r][1]*wb1 + Gg[r][2]*wb2;
      *(unsigned short*)(BA + r*512 + ((c*2) ^ ((r & 7) << 4))) = f2b(fmaxf(v2, 0.f));
    }
  }
  __syncthreads();
  // h_geo = fc(regs) + H2 @ m2w2 + b -> BB
  {
    f32x4 acc[4][2] = {};
    wg_gemm_reg(m2w2T, BA, tid, acc);
    wg_epi_fc(acc, BB, m2b2, fcf, tid);
  }
  // ---- H1 = relu(G @ w1a + b1a) -> BA ----
  {
    const int c = tid & 255;
    const int r0 = (tid >> 8) * 32;
    const float wa0 = w1a[c], wa1 = w1a[256+c], wa2 = w1a[512+c], wa3 = w1a[768+c];
    const float ba  = b1a[c];
    for (int r = r0; r < r0 + 32; r++){
      float v1 = ba + Gg[r][0]*wa0 + Gg[r][1]*wa1 + Gg[r][2]*wa2 + Gg[r][3]*wa3;
      *(unsigned short*)(BA + r*512 + ((c*2) ^ ((r & 7) << 4))) = f2b(fmaxf(v1, 0.f));
    }
  }
  __syncthreads();
  // h_pos = fc(regs) + H1 @ m1w2 + b -> REGISTERS (packed bf16); fcf dies here
  unsigned int hp[4][2][2];
  {
    f32x4 acc[4][2] = {};
    wg_gemm_reg(m1w2T, BA, tid, acc);
    wg_epi_regs(acc, m1b2, fcf, hp, tid);
    __syncthreads();                     // all A-reads of BA done
  }
  // q = h_geo @ wq(/16) -> BA
  {
    f32x4 acc[4][2] = {};
    wg_gemm_reg(wqT, BB, tid, acc);
    wg_epi_plain(acc, BA, tid);
  }
  // k = h_geo @ wk -> BB in place
  {
    f32x4 acc[4][2] = {};
    wg_gemm_reg(wkT, BB, tid, acc);
    __syncthreads();                     // all A-reads of BB done
    wg_epi_plain(acc, BB, tid);
  }

  // ---- S = q k^T in registers, softmax in registers -> Pm (bf16) ----
  if (CS == 64){
    const int tr = wave & 3, tc0 = wave >> 2;   // tiles (tr,tc0) and (tr,tc0+2)
    f32x4 sacc[2] = {};
    const int qrow = tr*16 + lrow;
    const int qsw  = (qrow & 7) << 4;
#pragma unroll
    for (int kk = 0; kk < 8; kk++){
      bf16x8 aq = *(const bf16x8*)(BA + qrow*512 + ((kk*64 + lq*16) ^ qsw));
#pragma unroll
      for (int c = 0; c < 2; c++){
        int brow = tc0*16 + c*32 + lrow;
        bf16x8 bk = *(const bf16x8*)(BB + brow*512 + ((kk*64 + lq*16) ^ ((brow & 7) << 4)));
        sacc[c] = __builtin_amdgcn_mfma_f32_16x16x32_bf16(aq, bk, sacc[c], 0, 0, 0);
      }
    }
    // per-row partial max & expsum across the 16-lane lrow group
    float fmx[4], fsm[4];
#pragma unroll
    for (int r = 0; r < 4; r++){
      float m = fmaxf(sacc[0][r], sacc[1][r]);
#pragma unroll
      for (int d = 1; d < 16; d <<= 1) m = fmaxf(m, __shfl_xor(m, d));
      float e0 = __expf(sacc[0][r] - m);
      float e1 = __expf(sacc[1][r] - m);
      sacc[0][r] = e0; sacc[1][r] = e1;
      float s = e0 + e1;
#pragma unroll
      for (int d = 1; d < 16; d <<= 1) s += __shfl_xor(s, d);
      fmx[r] = m; fsm[r] = s;
    }
    if (lrow == 0){
#pragma unroll
      for (int r = 0; r < 4; r++){
        int row = tr*16 + lq*4 + r;
        smx[row][tc0] = fmx[r];
        ssm[row][tc0] = fsm[r];
      }
    }
    __syncthreads();
#pragma unroll
    for (int r = 0; r < 4; r++){
      int row = tr*16 + lq*4 + r;
      float m0v = smx[row][0], m1v = smx[row][1];
      float M = fmaxf(m0v, m1v);
      float S = ssm[row][0]*__expf(m0v - M) + ssm[row][1]*__expf(m1v - M);
      float f = __expf((tc0 ? m1v : m0v) - M) / S;
      int sw = (row & 7) << 4;
#pragma unroll
      for (int c = 0; c < 2; c++){
        int col = tc0*16 + c*32 + lrow;
        *(unsigned short*)(Pm + row*128 + ((col*2) ^ sw)) = f2b(sacc[c][r]*f);
      }
    }
    __syncthreads();
  } else {
    if (wave < 4){
      f32x4 sacc = {};
      const int qrow = wave*16 + lrow;
      const int qsw  = (qrow & 7) << 4;
#pragma unroll
      for (int kk = 0; kk < 8; kk++){
        bf16x8 aq = *(const bf16x8*)(BA + qrow*512 + ((kk*64 + lq*16) ^ qsw));
        bf16x8 bk = *(const bf16x8*)(BB + qrow*512 + ((kk*64 + lq*16) ^ qsw));
        sacc = __builtin_amdgcn_mfma_f32_16x16x32_bf16(aq, bk, sacc, 0, 0, 0);
      }
#pragma unroll
      for (int r = 0; r < 4; r++){
        float m = sacc[r];
#pragma unroll
        for (int d = 1; d < 16; d <<= 1) m = fmaxf(m, __shfl_xor(m, d));
        float e = __expf(sacc[r] - m);
        float s = e;
#pragma unroll
        for (int d = 1; d < 16; d <<= 1) s += __shfl_xor(s, d);
        int row = wave*16 + lq*4 + r;
        *(unsigned short*)(Pm + row*64 + ((lrow*2) ^ ((row & 3) << 4))) = f2b(e / s);
      }
    } else {
      int t2 = tid - 256;            // 0..255: zero-pad P cols 16..31
      int row = t2 >> 2, j = t2 & 3;
      u16x4 z = {};
      *(u16x4*)(Pm + row*64 + ((32 + j*8) ^ ((row & 3) << 4))) = z;
    }
    __syncthreads();
  }

  // ---- h_pos regs -> BA (q dead); v = h_pos @ wv -> VT (BB) ----
  {
    const int col0 = wave*32 + lrow;
#pragma unroll
    for (int mt = 0; mt < 4; mt++)
#pragma unroll
      for (int nt = 0; nt < 2; nt++)
#pragma unroll
        for (int p = 0; p < 2; p++){
          int col = col0 + nt*16;
          int row0 = mt*16 + lq*4 + 2*p;
          unsigned int d = hp[mt][nt][p];
          *(unsigned short*)(BA + row0*512 + ((col*2) ^ ((row0 & 7) << 4))) = (unsigned short)d;
          int row1 = row0 + 1;
          *(unsigned short*)(BA + row1*512 + ((col*2) ^ ((row1 & 7) << 4))) = (unsigned short)(d >> 16);
        }
  }
  __syncthreads();
  {
    f32x4 acc[4][2] = {};
    wg_gemm_reg(wvT, BA, tid, acc);
    wg_epi_vt(acc, BB, tid);             // k (BB) dead since S-phase sync
  }

  // ---- O = P @ V -> BA (h_pos LDS copy dead after v-GEMM) ----
  {
    f32x4 oacc[4][2] = {};
    const int dbase = wave * 32;
    if (CS == 64){
#pragma unroll
      for (int kk = 0; kk < 2; kk++){
        bf16x8 ap[4];
#pragma unroll
        for (int mt = 0; mt < 4; mt++){
          int row = mt*16 + lrow;
          ap[mt] = *(const bf16x8*)(Pm + row*128 + ((kk*64 + lq*16) ^ ((row & 7) << 4)));
        }
#pragma unroll
        for (int nt = 0; nt < 2; nt++){
          const int d = dbase + nt*16 + lrow;
          bf16x8 bv = *(const bf16x8*)(BB + d*128 + ((kk*64 + lq*16) ^ ((d & 7) << 4)));
#pragma unroll
          for (int mt = 0; mt < 4; mt++)
            oacc[mt][nt] = __builtin_amdgcn_mfma_f32_16x16x32_bf16(ap[mt], bv, oacc[mt][nt], 0, 0, 0);
        }
      }
    } else {
#pragma unroll
      for (int mt = 0; mt < 4; mt++){
        int row = mt*16 + lrow;
        bf16x8 ap = *(const bf16x8*)(Pm + row*64 + ((lq*16) ^ ((row & 3) << 4)));
#pragma unroll
        for (int nt = 0; nt < 2; nt++){
          const int d = dbase + nt*16 + lrow;
          bf16x8 bv = *(const bf16x8*)(BB + d*128 + ((mt*32 + (lq & 1)*16) ^ ((d & 7) << 4)));
          oacc[mt][nt] = __builtin_amdgcn_mfma_f32_16x16x32_bf16(ap, bv, oacc[mt][nt], 0, 0, 0);
        }
      }
    }
    // BA reads all finished at epi_vt's barrier; safe to overwrite.
#pragma unroll
    for (int mt = 0; mt < 4; mt++){
#pragma unroll
      for (int nt = 0; nt < 2; nt++){
#pragma unroll
        for (int r = 0; r < 4; r++){
          int row = mt*16 + lq*4 + r;
          int col = dbase + nt*16 + lrow;
          *(unsigned short*)(BA + row*512 + ((col*2) ^ ((row & 7) << 4))) = f2b(oacc[mt][nt][r]);
        }
      }
    }
    __syncthreads();
  }

  // ---- y = O @ wo (regs); z = y + bo + hp(regs) -> BA; LN -> out ----
  {
    f32x4 yacc[4][2] = {};
    wg_gemm_reg(woT, BA, tid, yacc);
    __syncthreads();                     // all O-reads of BA done
    const int col0 = wave*32 + lrow;
#pragma unroll
    for (int mt = 0; mt < 4; mt++){
#pragma unroll
      for (int nt = 0; nt < 2; nt++){
        const int col = col0 + nt*16;
        const float bov = bo[col];
#pragma unroll
        for (int p = 0; p < 2; p++){
          unsigned int d = hp[mt][nt][p];
          int row0 = mt*16 + lq*4 + 2*p;
          float z0 = yacc[mt][nt][2*p]   + bov + b2f((unsigned short)d);
          float z1 = yacc[mt][nt][2*p+1] + bov + b2f((unsigned short)(d >> 16));
          *(unsigned short*)(BA + row0*512 + ((col*2) ^ ((row0 & 7) << 4))) = f2b(z0);
          int row1 = row0 + 1;
          *(unsigned short*)(BA + row1*512 + ((col*2) ^ ((row1 & 7) << 4))) = f2b(z1);
        }
      }
    }
    __syncthreads();
  }
  {
    const int row = tid >> 3, part = tid & 7;
    const size_t gr = (size_t)row * 256;
    const int sw = (row & 7) << 4;
    float sm = 0.f, sq = 0.f;
#pragma unroll
    for (int i = 0; i < 4; i++){
      int col = part*32 + i*8;
      u16x8 v = *(const u16x8*)(BA + row*512 + ((col*2) ^ sw));
#pragma unroll
      for (int j = 0; j < 8; j++){
        float y = b2f(v[j]);
        sm += y; sq += y*y;
      }
    }
    sred[row][part] = sm; s2red[row][part] = sq;
    __syncthreads();
    if (tid < 64){
      float s = 0.f, q2 = 0.f;
#pragma unroll
      for (int p = 0; p < 8; p++){ s += sred[tid][p]; q2 += s2red[tid][p]; }
      float mu = s * (1.0f/256.0f);
      float var = q2 * (1.0f/256.0f) - mu*mu;
      mub[tid] = mu;
      rsb[tid] = rsqrtf(var + 1e-5f);
    }
    __syncthreads();
    const float mu = mub[row], rs = rsb[row];
#pragma unroll
    for (int i = 0; i < 4; i++){
      int col = part*32 + i*8;
      u16x8 v = *(const u16x8*)(BA + row*512 + ((col*2) ^ sw));
      u16x8 o;
#pragma unroll
      for (int j = 0; j < 8; j++)
        o[j] = f2b((b2f(v[j]) - mu)*rs*lgam[col + j] + lbet[col + j]);
      *(u16x8*)(gout + gr + col) = o;
    }
  }
}

// ---------------------------------------------------------------------------
// Output: pos_ds gather + KNN max-pool.
// ---------------------------------------------------------------------------
__global__ __launch_bounds__(256) void out_k(
    const unsigned short* __restrict__ F2,
    const float* __restrict__ pos,
    const int* __restrict__ fps,
    const int* __restrict__ knn,
    float* __restrict__ outp)
{
  const int p = blockIdx.x;
  const int b = p >> 11;
  const int t = threadIdx.x;
  const int* kn = knn + (size_t)p * 16;
  const int c = t * 2;
  float m1 = -3.0e38f, m2 = -3.0e38f;
  for (int j = 0; j < 16; j++){
    int idx = kn[j];
    size_t row = ((size_t)b * 8192 + idx) * 512;
    u16x2 v = *(const u16x2*)(F2 + row + c);
    m1 = fmaxf(m1, b2f(v.x));
    m2 = fmaxf(m2, b2f(v.y));
  }
  float* of = outp + 49152 + (size_t)p * 512 + c;
  float2 o; o.x = m1; o.y = m2;
  *(float2*)of = o;
  if (t < 3){
    int fi = fps[p];
    outp[(size_t)p*3 + t] = pos[((size_t)b*8192 + fi)*3 + t];
  }
}

// ---------------------------------------------------------------------------
extern "C" void kernel_launch(void* const* d_in, const int* in_sizes, int n_in,
                              void* d_out, int out_size, void* d_ws, size_t ws_size,
                              hipStream_t stream)
{
  (void)in_sizes; (void)n_in; (void)out_size; (void)ws_size;

  const float* pos  = (const float*)d_in[0];
  const float* feat = (const float*)d_in[1];
  const int*   fps  = (const int*)d_in[2];
  const int*   knn  = (const int*)d_in[3];
  const float* m1w1 = (const float*)d_in[6];
  const float* m1b1 = (const float*)d_in[7];
  const float* m1w2 = (const float*)d_in[8];
  const float* m1b2 = (const float*)d_in[9];
  const float* m2w1 = (const float*)d_in[10];
  const float* m2b1 = (const float*)d_in[11];
  const float* m2w2 = (const float*)d_in[12];
  const float* m2b2 = (const float*)d_in[13];
  const float* wq   = (const float*)d_in[14];
  const float* wk   = (const float*)d_in[15];
  const float* wv   = (const float*)d_in[16];
  const float* wo   = (const float*)d_in[17];
  const float* bo   = (const float*)d_in[18];
  const float* lng  = (const float*)d_in[19];
  const float* lnb  = (const float*)d_in[20];
  const float* tdw  = (const float*)d_in[21];
  const float* tdb  = (const float*)d_in[22];
  const float* bng  = (const float*)d_in[23];
  const float* bnb  = (const float*)d_in[24];
  const float* bnm  = (const float*)d_in[25];
  const float* bnv  = (const float*)d_in[26];

  char* ws = (char*)d_ws;
  unsigned short* wT = (unsigned short*)ws;
  float* bns = (float*)(ws + 1835008);
  float* bnt = (float*)(ws + 1837056);
  const size_t SLOT = 33554432;
  unsigned short* A  = (unsigned short*)(ws + 2097152);
  unsigned short* Bs = (unsigned short*)(ws + 2097152 + SLOT);
  unsigned short* E  = (unsigned short*)(ws + 2097152 + 2*SLOT);

  auto wtm = [&](int mat, int i){ return wT + (size_t)mat*131072 + (size_t)i*65536; };
  unsigned short* tdT = wT + 786432;

  prep_k<<<3586, 256, 0, stream>>>(m1w2, m2w2, wq, wk, wv, wo, tdw, tdb, bng, bnb, bnm, bnv,
                                   wT, bns, bnt);

  block_k<16, true><<<1024, 512, 0, stream>>>(
      pos, feat, nullptr,
      m1w1, m1b1, m2w1, m2b1,
      wtm(0,0), m1b2, wtm(1,0), m2b2,
      wtm(2,0), wtm(3,0), wtm(4,0), wtm(5,0),
      bo, lng, lnb, A);

  block_k<64, false><<<1024, 512, 0, stream>>>(
      pos, nullptr, A,
      m1w1 + 1024, m1b1 + 256, m2w1 + 1536, m2b1 + 256,
      wtm(0,1), m1b2 + 256, wtm(1,1), m2b2 + 256,
      wtm(2,1), wtm(3,1), wtm(4,1), wtm(5,1),
      bo + 256, lng + 256, lnb + 256, Bs);

  gemm_k<<<dim3(512,4), 256, 0, stream>>>(Bs, tdT, E, nullptr, nullptr, bns, bnt, 512);

  out_k<<<16384, 256, 0, stream>>>(E, pos, fps, knn, (float*)d_out);
}